// Round 3
// baseline (667.298 us; speedup 1.0000x reference)
//
#include <hip/hip_runtime.h>
#include <math.h>

typedef float f4 __attribute__((ext_vector_type(4)));

// K0: segment start offsets from sorted segment ids.
// segstart[b] = first n with seg[n] >= b ; segstart[B] = N. Covers empty segs.
__global__ __launch_bounds__(256) void k_segstart(
        const int* __restrict__ seg, int* __restrict__ segstart, int N, int B) {
    int i = blockIdx.x * blockDim.x + threadIdx.x;
    if (i >= N) return;
    int s = seg[i];
    int p = (i == 0) ? -1 : seg[i - 1];
    for (int bb = p + 1; bb <= s; ++bb) segstart[bb] = i;
    if (i == N - 1)
        for (int bb = s + 1; bb <= B; ++bb) segstart[bb] = N;
}

// ---- cross-lane 32-sum: 4 DPP VALU adds + 1 ds_swizzle (xor16) ----
// After xor1,xor2 the quad is uniform, so row_half_mirror (i^7) == xor4;
// after that the 8-group is uniform, so row_mirror (i^15) == xor8.
// (verified correct on HW in the previous round: absmax unchanged)
template <int CTRL>
__device__ __forceinline__ float dpp_add(float v) {
    int sh = __builtin_amdgcn_update_dpp(0, __float_as_int(v), CTRL, 0xF, 0xF,
                                         false);
    return v + __int_as_float(sh);
}
__device__ __forceinline__ float halfwave_sum(float v) {
    v = dpp_add<0xB1>(v);   // quad_perm [1,0,3,2]  : xor1
    v = dpp_add<0x4E>(v);   // quad_perm [2,3,0,1]  : xor2
    v = dpp_add<0x141>(v);  // row_half_mirror      : xor4 (quads uniform)
    v = dpp_add<0x140>(v);  // row_mirror           : xor8 (8-grps uniform)
    int sw = __builtin_amdgcn_ds_swizzle(__float_as_int(v), 0x401F);  // xor16
    return v + __int_as_float(sw);
}

// K1: TWO blocks per segment (grid = 2B). 256 threads = 8 row-groups x 32
// column-lanes. Each block streams its half of the segment ONCE:
// unguarded full 32-row chunks (4 rows/group, depth-1 prefetch), DPP
// butterfly for the gate dot, batched-max online softmax (one conditional
// rescale + 4 independent exps). Raw gate g -> gbuf. Block partial
// (M_p, S_p, acc_p[128]) -> workspace; k_combine merges the two halves.
__global__ __launch_bounds__(256) void k_pool_partial(
        const float* __restrict__ feat, const float* __restrict__ w,
        const float* __restrict__ bptr, const int* __restrict__ segstart,
        float* __restrict__ gbuf, float* __restrict__ pm,
        float* __restrict__ ps, f4* __restrict__ pacc) {
    const int bp = blockIdx.x;
    const int b = bp >> 1, half = bp & 1;
    const int start = segstart[b], end = segstart[b + 1];
    const int len = end - start;
    const int hlen = (len + 1) >> 1;
    const int s0 = start + half * hlen;
    const int e0 = (s0 + hlen < end) ? (s0 + hlen) : end;

    const int t = threadIdx.x, rg = t >> 5, cl = t & 31;
    const bool cl0 = (cl == 0);

    const f4 w4 = ((const f4*)w)[cl];
    const float bias = bptr[0];
    const f4* featv = (const f4*)feat;

    float m = -INFINITY, s = 0.0f;
    f4 acc = (f4)0.0f;

    const int plen = (e0 > s0) ? (e0 - s0) : 0;
    const int nfull = plen >> 5;  // full 32-row chunks
    const f4* rowp = featv + ((size_t)s0 + rg) * 32 + cl;

    f4 f0, f1, f2, f3;

#define PROCESS4(rowbase)                                                     \
    do {                                                                      \
        float g0 = f0.x * w4.x + f0.y * w4.y + f0.z * w4.z + f0.w * w4.w;     \
        float g1 = f1.x * w4.x + f1.y * w4.y + f1.z * w4.z + f1.w * w4.w;     \
        float g2 = f2.x * w4.x + f2.y * w4.y + f2.z * w4.z + f2.w * w4.w;     \
        float g3 = f3.x * w4.x + f3.y * w4.y + f3.z * w4.z + f3.w * w4.w;     \
        g0 = dpp_add<0xB1>(g0); g1 = dpp_add<0xB1>(g1);                       \
        g2 = dpp_add<0xB1>(g2); g3 = dpp_add<0xB1>(g3);                       \
        g0 = dpp_add<0x4E>(g0); g1 = dpp_add<0x4E>(g1);                       \
        g2 = dpp_add<0x4E>(g2); g3 = dpp_add<0x4E>(g3);                       \
        g0 = dpp_add<0x141>(g0); g1 = dpp_add<0x141>(g1);                     \
        g2 = dpp_add<0x141>(g2); g3 = dpp_add<0x141>(g3);                     \
        g0 = dpp_add<0x140>(g0); g1 = dpp_add<0x140>(g1);                     \
        g2 = dpp_add<0x140>(g2); g3 = dpp_add<0x140>(g3);                     \
        g0 += __int_as_float(__builtin_amdgcn_ds_swizzle(                     \
                 __float_as_int(g0), 0x401F)) + bias;                         \
        g1 += __int_as_float(__builtin_amdgcn_ds_swizzle(                     \
                 __float_as_int(g1), 0x401F)) + bias;                         \
        g2 += __int_as_float(__builtin_amdgcn_ds_swizzle(                     \
                 __float_as_int(g2), 0x401F)) + bias;                         \
        g3 += __int_as_float(__builtin_amdgcn_ds_swizzle(                     \
                 __float_as_int(g3), 0x401F)) + bias;                         \
        if (cl0) {                                                            \
            gbuf[(rowbase)] = g0;                                             \
            gbuf[(rowbase) + 8] = g1;                                         \
            gbuf[(rowbase) + 16] = g2;                                        \
            gbuf[(rowbase) + 24] = g3;                                        \
        }                                                                     \
        float gm = fmaxf(fmaxf(g0, g1), fmaxf(g2, g3));                       \
        if (gm > m) {                                                         \
            float r = __expf(m - gm); /* exp(-inf)=0 on first chunk */        \
            s *= r; acc *= r; m = gm;                                         \
        }                                                                     \
        float e0_ = __expf(g0 - m), e1_ = __expf(g1 - m);                     \
        float e2_ = __expf(g2 - m), e3_ = __expf(g3 - m);                     \
        s += (e0_ + e1_) + (e2_ + e3_);                                       \
        acc += f0 * e0_; acc += f1 * e1_;                                     \
        acc += f2 * e2_; acc += f3 * e3_;                                     \
    } while (0)

    if (nfull > 0) {
        f0 = rowp[0];
        f1 = rowp[256];
        f2 = rowp[512];
        f3 = rowp[768];
        #pragma unroll 2
        for (int it = 1; it < nfull; ++it) {
            const f4* nx = rowp + (size_t)it * 1024;  // +32 rows
            f4 p0 = nx[0], p1 = nx[256], p2 = nx[512], p3 = nx[768];
            PROCESS4(s0 + rg + (it - 1) * 32);
            f0 = p0; f1 = p1; f2 = p2; f3 = p3;
        }
        PROCESS4(s0 + rg + (nfull - 1) * 32);
    }

    // guarded tail: < 32 remaining rows, one row per group per step
    for (int n = s0 + nfull * 32 + rg; n < e0; n += 8) {
        f4 ft = featv[(size_t)n * 32 + cl];
        float g = halfwave_sum(ft.x * w4.x + ft.y * w4.y + ft.z * w4.z +
                               ft.w * w4.w) + bias;
        if (cl0) gbuf[n] = g;
        if (g > m) {
            float r = __expf(m - g);
            s *= r; acc *= r; m = g;
        }
        float e = __expf(g - m);
        s += e;
        acc += ft * e;
    }

    // ---- combine the 8 row-groups into the block partial ----
    __shared__ float mred[8], sred[8];
    if (cl0) { mred[rg] = m; sred[rg] = s; }
    __syncthreads();
    float M = -INFINITY;
    #pragma unroll
    for (int g2 = 0; g2 < 8; ++g2) M = fmaxf(M, mred[g2]);
    float S = 0.0f;
    #pragma unroll
    for (int g2 = 0; g2 < 8; ++g2)
        if (sred[g2] > 0.0f) S += sred[g2] * __expf(mred[g2] - M);

    // rescale this group's accumulator to the block max (guard empty group)
    float r = (s > 0.0f) ? __expf(m - M) : 0.0f;
    acc *= r;

    __shared__ f4 red[256];
    red[t] = acc;
    __syncthreads();
    #pragma unroll
    for (int off = 4; off >= 1; off >>= 1) {
        if (rg < off) red[t] += red[t + off * 32];
        __syncthreads();
    }
    if (rg == 0) pacc[(size_t)bp * 32 + cl] = red[t];
    if (t == 0) { pm[bp] = M; ps[bp] = S; }
}

// K1b: merge the two half-partials of each segment; write readout, M, inv.
__global__ __launch_bounds__(64) void k_combine(
        const float* __restrict__ pm, const float* __restrict__ ps,
        const f4* __restrict__ pacc, float* __restrict__ Mbuf,
        float* __restrict__ invbuf, float* __restrict__ readout) {
    const int b = blockIdx.x, t = threadIdx.x;
    const float M0 = pm[2 * b], M1 = pm[2 * b + 1];
    const float S0 = ps[2 * b], S1 = ps[2 * b + 1];
    const float M = fmaxf(M0, M1);
    const float c0 = (S0 > 0.0f) ? __expf(M0 - M) : 0.0f;
    const float c1 = (S1 > 0.0f) ? __expf(M1 - M) : 0.0f;
    const float S = S0 * c0 + S1 * c1;
    const float inv = (S > 0.0f) ? 1.0f / S : 0.0f;
    if (t == 0) { Mbuf[b] = M; invbuf[b] = inv; }
    if (t < 32) {
        f4 a0 = pacc[(size_t)(2 * b) * 32 + t];
        f4 a1 = pacc[(size_t)(2 * b + 1) * 32 + t];
        f4 rr = a0 * c0 + a1 * c1;
        rr *= inv;
        ((f4*)readout)[(size_t)b * 32 + t] = rr;
    }
}

// K2: alpha[n] = exp(g[n] - M[seg[n]]) * inv[seg[n]]. ~12 MB traffic.
__global__ __launch_bounds__(256) void k_alpha(
        const float* __restrict__ gbuf, const int* __restrict__ seg,
        const float* __restrict__ Mbuf, const float* __restrict__ invbuf,
        float* __restrict__ alpha, int N) {
    int i = blockIdx.x * blockDim.x + threadIdx.x;
    int i4 = i * 4;
    if (i4 + 3 < N) {
        f4 g = ((const f4*)gbuf)[i];
        int4 sv = ((const int4*)seg)[i];
        f4 a;
        a.x = __expf(g.x - Mbuf[sv.x]) * invbuf[sv.x];
        a.y = __expf(g.y - Mbuf[sv.y]) * invbuf[sv.y];
        a.z = __expf(g.z - Mbuf[sv.z]) * invbuf[sv.z];
        a.w = __expf(g.w - Mbuf[sv.w]) * invbuf[sv.w];
        ((f4*)alpha)[i] = a;
    } else if (i4 < N) {
        for (int k = i4; k < N; ++k) {
            int sb = seg[k];
            alpha[k] = __expf(gbuf[k] - Mbuf[sb]) * invbuf[sb];
        }
    }
}

extern "C" void kernel_launch(void* const* d_in, const int* in_sizes, int n_in,
                              void* d_out, int out_size, void* d_ws, size_t ws_size,
                              hipStream_t stream) {
    const float* feat  = (const float*)d_in[0];
    const float* wgate = (const float*)d_in[1];
    const float* bgate = (const float*)d_in[2];
    const int*   seg   = (const int*)d_in[3];

    const int N = in_sizes[3];              // 1,000,000 nodes
    const int D = in_sizes[1];              // 128
    const int B = (out_size - N) / D;       // 1024 graphs

    float* readout = (float*)d_out;                    // [B,128]
    float* alpha   = (float*)d_out + (size_t)B * 128;  // [N]

    // workspace: segstart | Mbuf,invbuf | pm,ps | pacc | gbuf (256B-aligned)
    char* ws = (char*)d_ws;
    int* segstart = (int*)ws;
    size_t off = (((size_t)(B + 1) * 4) + 255) & ~(size_t)255;
    float* Mbuf = (float*)(ws + off);
    float* invbuf = Mbuf + B;
    off = (off + (size_t)2 * B * 4 + 255) & ~(size_t)255;
    float* pm = (float*)(ws + off);
    float* ps = pm + 2 * B;
    off = (off + (size_t)4 * B * 4 + 255) & ~(size_t)255;
    f4* pacc = (f4*)(ws + off);
    off = (off + (size_t)2 * B * 128 * 4 + 255) & ~(size_t)255;
    float* gbuf = (float*)(ws + off);

    k_segstart<<<(N + 255) / 256, 256, 0, stream>>>(seg, segstart, N, B);
    k_pool_partial<<<2 * B, 256, 0, stream>>>(feat, wgate, bgate, segstart,
                                              gbuf, pm, ps, pacc);
    k_combine<<<B, 64, 0, stream>>>(pm, ps, pacc, Mbuf, invbuf, readout);
    int threads4 = (N + 3) / 4;
    k_alpha<<<(threads4 + 255) / 256, 256, 0, stream>>>(gbuf, seg, Mbuf, invbuf,
                                                        alpha, N);
}

// Round 5
// 631.651 us; speedup vs baseline: 1.0564x; 1.0564x over previous
//
#include <hip/hip_runtime.h>
#include <math.h>

typedef float f4 __attribute__((ext_vector_type(4)));
typedef int i4 __attribute__((ext_vector_type(4)));

// K0: segment start offsets from sorted segment ids.
// segstart[b] = first n with seg[n] >= b ; segstart[B] = N. Covers empty segs.
__global__ __launch_bounds__(256) void k_segstart(
        const int* __restrict__ seg, int* __restrict__ segstart, int N, int B) {
    int i = blockIdx.x * blockDim.x + threadIdx.x;
    if (i >= N) return;
    int s = seg[i];
    int p = (i == 0) ? -1 : seg[i - 1];
    for (int bb = p + 1; bb <= s; ++bb) segstart[bb] = i;
    if (i == N - 1)
        for (int bb = s + 1; bb <= B; ++bb) segstart[bb] = N;
}

// Nontemporal f4 load: feat is read exactly once by exactly one block
// (zero reuse), so bypass L2/L3 allocation instead of thrashing them with
// 512 MB of single-use lines. NOTE: builtin requires a native ext_vector
// type, not HIP_vector_type (float4) — hence the f4 typedef.
__device__ __forceinline__ f4 ldnt(const f4* p) {
    return __builtin_nontemporal_load(p);
}

// K1: one block per segment. 256 threads = 8 row-groups x 32 column-lanes.
// SINGLE streaming pass over feat: per row compute gate g (partial dot +
// 5-step butterfly), online-update (m, s) AND the rescaled weighted
// accumulator acc = sum exp(g-m)*f. Raw g is stored to workspace so a tiny
// third kernel can emit alpha. Rows are processed 4 at a time so the four
// butterfly chains (5 dependent cross-lane ops each) are independent and
// overlap; next 4 rows are prefetched during the reduce.
// This exact structure measured 641 us (best of R1/R2/R3); the only change
// this round is the nontemporal hint on the feat stream (+ alpha store).
__global__ __launch_bounds__(256) void k_pool(
        const float* __restrict__ feat, const float* __restrict__ w,
        const float* __restrict__ bptr, const int* __restrict__ segstart,
        float* __restrict__ gbuf, float* __restrict__ Mbuf,
        float* __restrict__ invbuf, float* __restrict__ readout) {
    int b = blockIdx.x;
    int start = segstart[b], end = segstart[b + 1];
    int t = threadIdx.x, rg = t >> 5, cl = t & 31;

    const f4 w4 = ((const f4*)w)[cl];
    const float bias = bptr[0];
    const f4* featv = (const f4*)feat;

    float m = -INFINITY, s = 0.0f;
    f4 acc = (f4)0.0f;

    const int n0 = start + rg;

#define LDROW(dst, row)                                                       \
    dst = ((row) < end) ? ldnt(&featv[(size_t)(row) * 32 + cl]) : (f4)0.0f

    f4 f0, f1, f2, f3;
    LDROW(f0, n0);
    LDROW(f1, n0 + 8);
    LDROW(f2, n0 + 16);
    LDROW(f3, n0 + 24);

#define UPDATE(v, f, row) do {                                                \
        if ((row) < end) {                                                    \
            float g = (v) + bias;                                             \
            if (cl == 0) gbuf[row] = g;                                       \
            float e;                                                          \
            if (g > m) {                                                      \
                float r = __expf(m - g);  /* exp(-inf)=0 on first row */      \
                s *= r;                                                       \
                acc *= r;                                                     \
                m = g; e = 1.0f;                                              \
            } else {                                                          \
                e = __expf(g - m);                                            \
            }                                                                 \
            s += e;                                                           \
            acc += f * e;                                                     \
        } } while (0)

    for (int n = n0; n < end; n += 32) {
        f4 p0, p1, p2, p3;
        LDROW(p0, n + 32);
        LDROW(p1, n + 40);
        LDROW(p2, n + 48);
        LDROW(p3, n + 56);

        float v0 = f0.x * w4.x + f0.y * w4.y + f0.z * w4.z + f0.w * w4.w;
        float v1 = f1.x * w4.x + f1.y * w4.y + f1.z * w4.z + f1.w * w4.w;
        float v2 = f2.x * w4.x + f2.y * w4.y + f2.z * w4.z + f2.w * w4.w;
        float v3 = f3.x * w4.x + f3.y * w4.y + f3.z * w4.z + f3.w * w4.w;
        // 4 independent butterfly chains, interleaved (xor<32 stays in half-wave)
        #pragma unroll
        for (int d = 1; d < 32; d <<= 1) {
            v0 += __shfl_xor(v0, d);
            v1 += __shfl_xor(v1, d);
            v2 += __shfl_xor(v2, d);
            v3 += __shfl_xor(v3, d);
        }

        UPDATE(v0, f0, n);
        UPDATE(v1, f1, n + 8);
        UPDATE(v2, f2, n + 16);
        UPDATE(v3, f3, n + 24);

        f0 = p0; f1 = p1; f2 = p2; f3 = p3;
    }

    // ---- combine the 8 row-groups ----
    __shared__ float mred[8], sred[8];
    if (cl == 0) { mred[rg] = m; sred[rg] = s; }
    __syncthreads();
    float M = -INFINITY;
    #pragma unroll
    for (int g2 = 0; g2 < 8; ++g2) M = fmaxf(M, mred[g2]);
    float S = 0.0f;
    #pragma unroll
    for (int g2 = 0; g2 < 8; ++g2)
        if (sred[g2] > 0.0f) S += sred[g2] * __expf(mred[g2] - M);
    const float inv = (S > 0.0f) ? 1.0f / S : 0.0f;

    // rescale this group's accumulator to the global max (guard empty group:
    // m-M would be -inf-(-inf)=NaN when s==0)
    float r = (s > 0.0f) ? __expf(m - M) : 0.0f;
    acc *= r;

    __shared__ f4 red[256];
    red[t] = acc;
    __syncthreads();
    #pragma unroll
    for (int off = 4; off >= 1; off >>= 1) {
        if (rg < off) red[t] += red[t + off * 32];
        __syncthreads();
    }
    if (rg == 0) {
        f4 o = red[t];
        o *= inv;
        ((f4*)(readout + (size_t)b * 128))[cl] = o;
    }
    if (t == 0) { Mbuf[b] = M; invbuf[b] = inv; }
}

// K2: alpha[n] = exp(g[n] - M[seg[n]]) * inv[seg[n]]. ~12 MB traffic.
// alpha is write-once, never re-read -> nontemporal store.
__global__ __launch_bounds__(256) void k_alpha(
        const float* __restrict__ gbuf, const int* __restrict__ seg,
        const float* __restrict__ Mbuf, const float* __restrict__ invbuf,
        float* __restrict__ alpha, int N) {
    int i = blockIdx.x * blockDim.x + threadIdx.x;
    int idx4 = i * 4;
    if (idx4 + 3 < N) {
        f4 g = ((const f4*)gbuf)[i];
        i4 sv = ((const i4*)seg)[i];
        f4 a;
        a.x = __expf(g.x - Mbuf[sv.x]) * invbuf[sv.x];
        a.y = __expf(g.y - Mbuf[sv.y]) * invbuf[sv.y];
        a.z = __expf(g.z - Mbuf[sv.z]) * invbuf[sv.z];
        a.w = __expf(g.w - Mbuf[sv.w]) * invbuf[sv.w];
        __builtin_nontemporal_store(a, &((f4*)alpha)[i]);
    } else if (idx4 < N) {
        for (int k = idx4; k < N; ++k) {
            int sb = seg[k];
            alpha[k] = __expf(gbuf[k] - Mbuf[sb]) * invbuf[sb];
        }
    }
}

extern "C" void kernel_launch(void* const* d_in, const int* in_sizes, int n_in,
                              void* d_out, int out_size, void* d_ws, size_t ws_size,
                              hipStream_t stream) {
    const float* feat  = (const float*)d_in[0];
    const float* wgate = (const float*)d_in[1];
    const float* bgate = (const float*)d_in[2];
    const int*   seg   = (const int*)d_in[3];

    const int N = in_sizes[3];              // 1,000,000 nodes
    const int D = in_sizes[1];              // 128
    const int B = (out_size - N) / D;       // 1024 graphs

    float* readout = (float*)d_out;                    // [B,128]
    float* alpha   = (float*)d_out + (size_t)B * 128;  // [N]

    // workspace layout: segstart | Mbuf | invbuf | gbuf (all 256B-aligned)
    int* segstart = (int*)d_ws;
    size_t off = (((size_t)(B + 1) * 4) + 255) & ~(size_t)255;
    float* Mbuf = (float*)((char*)d_ws + off);
    float* invbuf = Mbuf + B;
    size_t off2 = (off + (size_t)2 * B * 4 + 255) & ~(size_t)255;
    float* gbuf = (float*)((char*)d_ws + off2);

    k_segstart<<<(N + 255) / 256, 256, 0, stream>>>(seg, segstart, N, B);
    k_pool<<<B, 256, 0, stream>>>(feat, wgate, bgate, segstart,
                                  gbuf, Mbuf, invbuf, readout);
    int threads4 = (N + 3) / 4;
    k_alpha<<<(threads4 + 255) / 256, 256, 0, stream>>>(gbuf, seg, Mbuf, invbuf,
                                                        alpha, N);
}